// Round 5
// baseline (792.482 us; speedup 1.0000x reference)
//
#include <hip/hip_runtime.h>
#include <hip/hip_cooperative_groups.h>

namespace cg = cooperative_groups;

// ---------------------------------------------------------------------------
// GPSLayer (GINE + global attention + FFN + 3x BatchNorm), MI355X gfx950.
// Single cooperative mega-kernel: 11 phases separated by grid.sync().
// fp32 in/out; internal bf16 MFMA with fp32 accumulation.
// ---------------------------------------------------------------------------

#define NNODES 16384
#define NEDGE  262144

typedef __bf16 bf16;
typedef __bf16 bf16x8 __attribute__((ext_vector_type(8)));
typedef float  f32x4  __attribute__((ext_vector_type(4)));

__device__ inline f32x4 mfma16(bf16x8 a, bf16x8 b, f32x4 c) {
  return __builtin_amdgcn_mfma_f32_16x16x32_bf16(a, b, c, 0, 0, 0);
}

struct PK {
  const float *x, *ea; const int* ei;
  const float *gw1, *gb1, *gw2, *gb2;
  const float *bn1l_g, *bn1l_b;
  const float *ipw, *ipb, *opw, *opb;
  const float *bn1a_g, *bn1a_b;
  const float *fw1, *fb1, *fw2, *fb2;
  const float *bn2_g, *bn2_b;
  bf16* W; float* stats; int *cnt, *off, *cur, *psum; int2* se;
  float *z, *hl, *ob, *ha, *h2, *out;
  bf16 *qb, *kb, *vb;
};

// LDS union layout (bytes):
//  gemm phases: Abf[32][136]bf16 @0 (8704) | Wl[128][136]bf16 @8704 (34816)
//               slds[256]f32 @43520 (1024) | Tt[32][264]bf16 @44544 (16896)
//               hbt[32][128]f32 @61440 (16384) | bnc[512]f32 @77824 (2048)
//  attn: Klds[512][16] @0 (16384) | Vlds[16][520] @16384 (16640)
//        Plds[4][16][136] @33024 (17408)
#define SMEM_BYTES 79872

__device__ inline void load_w(const bf16* __restrict__ src, int ks,
                              bf16* __restrict__ Wl, int tid) {
  int n = tid >> 1, c = (tid & 1) * 64;
  const bf16* s = src + (size_t)n * ks + c;
  bf16* d = Wl + n * 136 + c;
#pragma unroll
  for (int j = 0; j < 8; ++j)
    *(bf16x8*)(d + j * 8) = *(const bf16x8*)(s + j * 8);
}

__device__ inline void load_a32(const float* __restrict__ src,
                                bf16* __restrict__ Al, int tid) {
  int r = tid >> 3, c = (tid & 7) * 16;
  const float* s = src + (size_t)r * 128 + c;
  float4 v0 = *(const float4*)s, v1 = *(const float4*)(s + 4);
  float4 v2 = *(const float4*)(s + 8), v3 = *(const float4*)(s + 12);
  *(bf16x8*)(Al + r * 136 + c) =
      (bf16x8){(bf16)v0.x, (bf16)v0.y, (bf16)v0.z, (bf16)v0.w,
               (bf16)v1.x, (bf16)v1.y, (bf16)v1.z, (bf16)v1.w};
  *(bf16x8*)(Al + r * 136 + c + 8) =
      (bf16x8){(bf16)v2.x, (bf16)v2.y, (bf16)v2.z, (bf16)v2.w,
               (bf16)v3.x, (bf16)v3.y, (bf16)v3.z, (bf16)v3.w};
}

__device__ inline void do_gemm(const bf16* __restrict__ A, int lda,
                               const bf16* __restrict__ Wl,
                               int rg, int chalf, int quad, int l16,
                               f32x4 acc[4]) {
#pragma unroll
  for (int kt = 0; kt < 4; ++kt) {
    bf16x8 af = *(const bf16x8*)(A + (rg * 16 + l16) * lda + kt * 32 + quad * 8);
#pragma unroll
    for (int nt = 0; nt < 4; ++nt) {
      bf16x8 bfr = *(const bf16x8*)(Wl + (chalf * 64 + nt * 16 + l16) * 136 +
                                    kt * 32 + quad * 8);
      acc[nt] = mfma16(af, bfr, acc[nt]);
    }
  }
}

__global__ __launch_bounds__(256, 2) void mega_k(PK p) {
  cg::grid_group grid = cg::this_grid();
  __shared__ __align__(16) char smem[SMEM_BYTES];
  bf16*  Abf  = (bf16*)smem;
  bf16*  Wl   = (bf16*)(smem + 8704);
  float* slds = (float*)(smem + 43520);
  bf16*  Tt   = (bf16*)(smem + 44544);
  float* hbt  = (float*)(smem + 61440);
  float* bnc  = (float*)(smem + 77824);
  bf16*  Klds = (bf16*)smem;
  bf16*  Vlds = (bf16*)(smem + 16384);
  bf16*  Plds = (bf16*)(smem + 33024);
  int*   ilds = (int*)smem;

  const int tid = threadIdx.x, bid = blockIdx.x, nb = gridDim.x;
  const int wave = tid >> 6, lane = tid & 63, quad = lane >> 4, l16 = lane & 15;
  const int rg = wave >> 1, chalf = wave & 1;
  const int gsz = nb * 256;

  // ---- P0: weights -> bf16 W; zero cnt, stats --------------------------
  for (int i = bid * 256 + tid; i < 163840 + 16384 + 768; i += gsz) {
    if (i < 16384) {
      p.W[i] = (bf16)p.gw1[(i & 127) * 128 + (i >> 7)];
    } else if (i < 32768) {
      int j = i - 16384;
      p.W[i] = (bf16)p.gw2[(j & 127) * 128 + (j >> 7)];
    } else if (i < 81920) {
      p.W[i] = (bf16)p.ipw[i - 32768];
    } else if (i < 98304) {
      p.W[i] = (bf16)p.opw[i - 81920];
    } else if (i < 131072) {
      int j = i - 98304;
      p.W[i] = (bf16)p.fw1[(j & 127) * 256 + (j >> 7)];
    } else if (i < 163840) {
      int j = i - 131072;
      p.W[i] = (bf16)p.fw2[(j & 255) * 128 + (j >> 8)];
    } else if (i < 163840 + 16384) {
      p.cnt[i - 163840] = 0;
    } else {
      p.stats[i - 163840 - 16384] = 0.f;
    }
  }
  grid.sync();
  // ---- P1: histogram of dst --------------------------------------------
  for (int e = bid * 256 + tid; e < NEDGE; e += gsz)
    atomicAdd(&p.cnt[p.ei[NEDGE + e]], 1);
  grid.sync();
  // ---- P2a: per-chunk (32 nodes) exclusive scan + chunk totals ---------
  for (int c = bid; c < 512; c += nb) {
    if (wave == 0) {
      int v = (lane < 32) ? p.cnt[c * 32 + lane] : 0;
      int xv = v;
#pragma unroll
      for (int d = 1; d < 32; d <<= 1) {
        int u = __shfl_up(xv, d, 64);
        if (lane >= d) xv += u;
      }
      if (lane < 32) p.off[c * 32 + lane] = xv - v;
      if (lane == 31) p.psum[c] = xv;
    }
  }
  grid.sync();
  // ---- P2b: block 0 scans 512 chunk totals (in-place exclusive) --------
  if (bid == 0) {
    int a = p.psum[2 * tid], b2 = p.psum[2 * tid + 1];
    ilds[tid] = a + b2;
    __syncthreads();
    for (int d = 1; d < 256; d <<= 1) {
      int y = (tid >= d) ? ilds[tid - d] : 0;
      __syncthreads();
      ilds[tid] += y;
      __syncthreads();
    }
    int base = (tid > 0) ? ilds[tid - 1] : 0;
    p.psum[2 * tid] = base;
    p.psum[2 * tid + 1] = base + a;
    if (tid == 255) p.off[16384] = ilds[255];
  }
  grid.sync();
  // ---- P2c: add chunk bases --------------------------------------------
  for (int i = bid * 256 + tid; i < 16384; i += gsz) {
    int o = p.off[i] + p.psum[i >> 5];
    p.off[i] = o;
    p.cur[i] = o;
  }
  grid.sync();
  // ---- P3: scatter (src, e) sorted by dst ------------------------------
  for (int e = bid * 256 + tid; e < NEDGE; e += gsz) {
    int s = p.ei[e], d = p.ei[NEDGE + e];
    int pos = atomicAdd(&p.cur[d], 1);
    p.se[pos] = make_int2(s, e);
  }
  grid.sync();
  // ---- P4: GINE aggregate, wave per node -------------------------------
  {
    int c2 = lane * 2;
    int nw = nb * 4;
    for (int node = bid * 4 + wave; node < NNODES; node += nw) {
      int o0 = p.off[node], o1 = p.off[node + 1];
      float a0 = 0.f, a1 = 0.f;
      int j = o0;
      for (; j + 4 <= o1; j += 4) {
        int2 q0 = p.se[j], q1 = p.se[j + 1], q2 = p.se[j + 2], q3 = p.se[j + 3];
        float2 x0 = *(const float2*)(p.x + (size_t)q0.x * 128 + c2);
        float2 e0 = *(const float2*)(p.ea + (size_t)q0.y * 128 + c2);
        float2 x1 = *(const float2*)(p.x + (size_t)q1.x * 128 + c2);
        float2 e1 = *(const float2*)(p.ea + (size_t)q1.y * 128 + c2);
        float2 x2 = *(const float2*)(p.x + (size_t)q2.x * 128 + c2);
        float2 e2 = *(const float2*)(p.ea + (size_t)q2.y * 128 + c2);
        float2 x3 = *(const float2*)(p.x + (size_t)q3.x * 128 + c2);
        float2 e3 = *(const float2*)(p.ea + (size_t)q3.y * 128 + c2);
        a0 += fmaxf(x0.x + e0.x, 0.f) + fmaxf(x1.x + e1.x, 0.f) +
              fmaxf(x2.x + e2.x, 0.f) + fmaxf(x3.x + e3.x, 0.f);
        a1 += fmaxf(x0.y + e0.y, 0.f) + fmaxf(x1.y + e1.y, 0.f) +
              fmaxf(x2.y + e2.y, 0.f) + fmaxf(x3.y + e3.y, 0.f);
      }
      for (; j < o1; ++j) {
        int2 q = p.se[j];
        float2 xe = *(const float2*)(p.x + (size_t)q.x * 128 + c2);
        float2 ae = *(const float2*)(p.ea + (size_t)q.y * 128 + c2);
        a0 += fmaxf(xe.x + ae.x, 0.f);
        a1 += fmaxf(xe.y + ae.y, 0.f);
      }
      float2 xn = *(const float2*)(p.x + (size_t)node * 128 + c2);
      *(float2*)(p.z + (size_t)node * 128 + c2) =
          make_float2(xn.x + a0, xn.y + a1);
    }
  }
  grid.sync();
  // ---- P5: fused GIN MLP (2 GEMMs, +stats1) + QKV ----------------------
  for (int ch = bid; ch < 512; ch += nb) {
    int m0 = ch * 32;
    int rowb = m0 + rg * 16 + quad * 4;
    slds[tid] = 0.f;
    load_a32(p.z + (size_t)m0 * 128, Abf, tid);
    load_w(p.W, 128, Wl, tid);
    __syncthreads();
    f32x4 acc[4];
#pragma unroll
    for (int t = 0; t < 4; ++t) acc[t] = (f32x4){0.f, 0.f, 0.f, 0.f};
    do_gemm(Abf, 136, Wl, rg, chalf, quad, l16, acc);
#pragma unroll
    for (int nt = 0; nt < 4; ++nt) {
      int col = chalf * 64 + nt * 16 + l16;
      float bv = p.gb1[col];
#pragma unroll
      for (int r = 0; r < 4; ++r) {
        float v = fmaxf(acc[nt][r] + bv, 0.f);
        Tt[(rg * 16 + quad * 4 + r) * 136 + col] = (bf16)v;
      }
    }
    __syncthreads();
    load_w(p.W + 16384, 128, Wl, tid);
    __syncthreads();
#pragma unroll
    for (int t = 0; t < 4; ++t) acc[t] = (f32x4){0.f, 0.f, 0.f, 0.f};
    do_gemm(Tt, 136, Wl, rg, chalf, quad, l16, acc);
#pragma unroll
    for (int nt = 0; nt < 4; ++nt) {
      int col = chalf * 64 + nt * 16 + l16;
      float bv = p.gb2[col];
      float vals[4];
#pragma unroll
      for (int r = 0; r < 4; ++r) {
        float v = acc[nt][r] + bv + p.x[(size_t)(rowb + r) * 128 + col];
        vals[r] = v;
        p.hl[(size_t)(rowb + r) * 128 + col] = v;
      }
      float s = vals[0] + vals[1] + vals[2] + vals[3];
      float q2 = vals[0] * vals[0] + vals[1] * vals[1] +
                 vals[2] * vals[2] + vals[3] * vals[3];
      s += __shfl_xor(s, 16); s += __shfl_xor(s, 32);
      q2 += __shfl_xor(q2, 16); q2 += __shfl_xor(q2, 32);
      if (quad == 0) {
        atomicAdd(&slds[col * 2], s);
        atomicAdd(&slds[col * 2 + 1], q2);
      }
    }
    __syncthreads();
    if (tid < 128) {
      atomicAdd(&p.stats[tid], slds[tid * 2]);
      atomicAdd(&p.stats[128 + tid], slds[tid * 2 + 1]);
    }
    load_a32(p.x + (size_t)m0 * 128, Abf, tid);
    for (int nc = 0; nc < 3; ++nc) {
      load_w(p.W + 32768 + nc * 16384, 128, Wl, tid);
      __syncthreads();
#pragma unroll
      for (int t = 0; t < 4; ++t) acc[t] = (f32x4){0.f, 0.f, 0.f, 0.f};
      do_gemm(Abf, 136, Wl, rg, chalf, quad, l16, acc);
      bf16* dst = (nc == 0) ? p.qb : ((nc == 1) ? p.kb : p.vb);
#pragma unroll
      for (int nt = 0; nt < 4; ++nt) {
        int col = chalf * 64 + nt * 16 + l16;
        float bv = p.ipb[nc * 128 + col];
#pragma unroll
        for (int r = 0; r < 4; ++r)
          dst[(size_t)(rowb + r) * 128 + col] = (bf16)(acc[nt][r] + bv);
      }
      __syncthreads();
    }
  }
  grid.sync();
  // ---- P6: attention ---------------------------------------------------
  for (int t6 = bid; t6 < 512; t6 += nb) {
    int half = t6 & 1, hh = (t6 >> 1) & 7, g = t6 >> 4;
    const size_t gbase = (size_t)g * 512 * 128 + hh * 16;
    for (int r = tid; r < 512; r += 256) {
      const bf16* src = p.kb + gbase + (size_t)r * 128;
      *(bf16x8*)&Klds[r * 16] = *(const bf16x8*)src;
      *(bf16x8*)&Klds[r * 16 + 8] = *(const bf16x8*)(src + 8);
    }
    for (int r = tid; r < 512; r += 256) {
      const bf16* src = p.vb + gbase + (size_t)r * 128;
#pragma unroll
      for (int d = 0; d < 16; ++d) Vlds[d * 520 + r] = src[d];
    }
    __syncthreads();
    const bf16x8 z8 = {};
    for (int it = 0; it < 4; ++it) {
      int qt = half * 16 + it * 4 + wave;
      bf16x8 qf = z8;
      if (quad < 2)
        qf = *(const bf16x8*)(p.qb + gbase + (size_t)(qt * 16 + l16) * 128 +
                              quad * 8);
      f32x4 S[32];
#pragma unroll
      for (int jt = 0; jt < 32; ++jt) {
        bf16x8 kf = z8;
        if (quad < 2) kf = *(const bf16x8*)&Klds[(jt * 16 + l16) * 16 + quad * 8];
        S[jt] = mfma16(kf, qf, (f32x4){0.f, 0.f, 0.f, 0.f});
      }
      float mx = -1e30f;
#pragma unroll
      for (int jt = 0; jt < 32; ++jt)
#pragma unroll
        for (int r = 0; r < 4; ++r) mx = fmaxf(mx, S[jt][r]);
      mx = fmaxf(mx, __shfl_xor(mx, 16));
      mx = fmaxf(mx, __shfl_xor(mx, 32));
      float sm = 0.f;
#pragma unroll
      for (int jt = 0; jt < 32; ++jt)
#pragma unroll
        for (int r = 0; r < 4; ++r) {
          float e = __expf((S[jt][r] - mx) * 0.25f);
          S[jt][r] = e;
          sm += e;
        }
      sm += __shfl_xor(sm, 16);
      sm += __shfl_xor(sm, 32);
      float rinv = 1.f / sm;
      f32x4 O = (f32x4){0.f, 0.f, 0.f, 0.f};
#pragma unroll
      for (int qd = 0; qd < 4; ++qd) {
#pragma unroll
        for (int jt2 = 0; jt2 < 8; ++jt2)
#pragma unroll
          for (int r = 0; r < 4; ++r)
            Plds[(wave * 16 + l16) * 136 + jt2 * 16 + quad * 4 + r] =
                (bf16)(S[qd * 8 + jt2][r] * rinv);
#pragma unroll
        for (int kt = 0; kt < 4; ++kt) {
          bf16x8 pf = *(const bf16x8*)&Plds[(wave * 16 + l16) * 136 + kt * 32 +
                                            quad * 8];
          bf16x8 vf = *(const bf16x8*)&Vlds[l16 * 520 + qd * 128 + kt * 32 +
                                            quad * 8];
          O = mfma16(vf, pf, O);
        }
      }
      *(float4*)(p.ob + (size_t)(g * 512 + qt * 16 + l16) * 128 + hh * 16 +
                 quad * 4) = make_float4(O[0], O[1], O[2], O[3]);
    }
    __syncthreads();
  }
  grid.sync();
  // ---- P7: out-proj + resid + stats2 -----------------------------------
  for (int ch = bid; ch < 512; ch += nb) {
    int m0 = ch * 32;
    int rowb = m0 + rg * 16 + quad * 4;
    slds[tid] = 0.f;
    load_a32(p.ob + (size_t)m0 * 128, Abf, tid);
    load_w(p.W + 81920, 128, Wl, tid);
    __syncthreads();
    f32x4 acc[4];
#pragma unroll
    for (int t = 0; t < 4; ++t) acc[t] = (f32x4){0.f, 0.f, 0.f, 0.f};
    do_gemm(Abf, 136, Wl, rg, chalf, quad, l16, acc);
#pragma unroll
    for (int nt = 0; nt < 4; ++nt) {
      int col = chalf * 64 + nt * 16 + l16;
      float bv = p.opb[col];
      float vals[4];
#pragma unroll
      for (int r = 0; r < 4; ++r) {
        float v = acc[nt][r] + bv + p.x[(size_t)(rowb + r) * 128 + col];
        vals[r] = v;
        p.ha[(size_t)(rowb + r) * 128 + col] = v;
      }
      float s = vals[0] + vals[1] + vals[2] + vals[3];
      float q2 = vals[0] * vals[0] + vals[1] * vals[1] +
                 vals[2] * vals[2] + vals[3] * vals[3];
      s += __shfl_xor(s, 16); s += __shfl_xor(s, 32);
      q2 += __shfl_xor(q2, 16); q2 += __shfl_xor(q2, 32);
      if (quad == 0) {
        atomicAdd(&slds[col * 2], s);
        atomicAdd(&slds[col * 2 + 1], q2);
      }
    }
    __syncthreads();
    if (tid < 128) {
      atomicAdd(&p.stats[256 + tid], slds[tid * 2]);
      atomicAdd(&p.stats[384 + tid], slds[tid * 2 + 1]);
    }
    __syncthreads();
  }
  grid.sync();
  // ---- P8: combine (bn1l+bn1a) + FFN (2 GEMMs) + stats3 ----------------
  for (int ch = bid; ch < 512; ch += nb) {
    int m0 = ch * 32;
    int rowb = m0 + rg * 16 + quad * 4;
    if (tid < 128) {
      const float inv = 1.f / 16384.f;
      float mu = p.stats[tid] * inv;
      float var = p.stats[128 + tid] * inv - mu * mu;
      float s = p.bn1l_g[tid] * rsqrtf(var + 1e-5f);
      bnc[tid] = s;
      bnc[128 + tid] = p.bn1l_b[tid] - mu * s;
      mu = p.stats[256 + tid] * inv;
      var = p.stats[384 + tid] * inv - mu * mu;
      s = p.bn1a_g[tid] * rsqrtf(var + 1e-5f);
      bnc[256 + tid] = s;
      bnc[384 + tid] = p.bn1a_b[tid] - mu * s;
    }
    slds[tid] = 0.f;
    __syncthreads();
    {
      int r = tid >> 3, c16 = (tid & 7) * 16;
#pragma unroll
      for (int j = 0; j < 4; ++j) {
        int c = c16 + j * 4;
        float4 a = *(const float4*)(p.hl + (size_t)(m0 + r) * 128 + c);
        float4 b = *(const float4*)(p.ha + (size_t)(m0 + r) * 128 + c);
        float4 o;
        o.x = a.x * bnc[c] + bnc[128 + c] + b.x * bnc[256 + c] + bnc[384 + c];
        o.y = a.y * bnc[c + 1] + bnc[129 + c] + b.y * bnc[257 + c] + bnc[385 + c];
        o.z = a.z * bnc[c + 2] + bnc[130 + c] + b.z * bnc[258 + c] + bnc[386 + c];
        o.w = a.w * bnc[c + 3] + bnc[131 + c] + b.w * bnc[259 + c] + bnc[387 + c];
        *(float4*)(hbt + r * 128 + c) = o;
        Abf[r * 136 + c] = (bf16)o.x;
        Abf[r * 136 + c + 1] = (bf16)o.y;
        Abf[r * 136 + c + 2] = (bf16)o.z;
        Abf[r * 136 + c + 3] = (bf16)o.w;
      }
    }
    f32x4 acc[4];
    for (int nc = 0; nc < 2; ++nc) {
      load_w(p.W + 98304 + nc * 16384, 128, Wl, tid);
      __syncthreads();
#pragma unroll
      for (int t = 0; t < 4; ++t) acc[t] = (f32x4){0.f, 0.f, 0.f, 0.f};
      do_gemm(Abf, 136, Wl, rg, chalf, quad, l16, acc);
#pragma unroll
      for (int nt = 0; nt < 4; ++nt) {
        int col = chalf * 64 + nt * 16 + l16;
        float bv = p.fb1[nc * 128 + col];
#pragma unroll
        for (int r = 0; r < 4; ++r) {
          float v = fmaxf(acc[nt][r] + bv, 0.f);
          Tt[(rg * 16 + quad * 4 + r) * 264 + nc * 128 + col] = (bf16)v;
        }
      }
      __syncthreads();
    }
    f32x4 acc2[4];
#pragma unroll
    for (int t = 0; t < 4; ++t) acc2[t] = (f32x4){0.f, 0.f, 0.f, 0.f};
    for (int kc = 0; kc < 2; ++kc) {
      load_w(p.W + 131072 + kc * 128, 256, Wl, tid);
      __syncthreads();
      do_gemm(Tt + kc * 128, 264, Wl, rg, chalf, quad, l16, acc2);
      __syncthreads();
    }
#pragma unroll
    for (int nt = 0; nt < 4; ++nt) {
      int col = chalf * 64 + nt * 16 + l16;
      float bv = p.fb2[col];
      float vals[4];
#pragma unroll
      for (int r = 0; r < 4; ++r) {
        float v = acc2[nt][r] + bv + hbt[(rg * 16 + quad * 4 + r) * 128 + col];
        vals[r] = v;
        p.h2[(size_t)(rowb + r) * 128 + col] = v;
      }
      float s = vals[0] + vals[1] + vals[2] + vals[3];
      float q2 = vals[0] * vals[0] + vals[1] * vals[1] +
                 vals[2] * vals[2] + vals[3] * vals[3];
      s += __shfl_xor(s, 16); s += __shfl_xor(s, 32);
      q2 += __shfl_xor(q2, 16); q2 += __shfl_xor(q2, 32);
      if (quad == 0) {
        atomicAdd(&slds[col * 2], s);
        atomicAdd(&slds[col * 2 + 1], q2);
      }
    }
    __syncthreads();
    if (tid < 128) {
      atomicAdd(&p.stats[512 + tid], slds[tid * 2]);
      atomicAdd(&p.stats[640 + tid], slds[tid * 2 + 1]);
    }
    __syncthreads();
  }
  grid.sync();
  // ---- P9: apply bn2 ---------------------------------------------------
  if (tid < 128) {
    const float inv = 1.f / 16384.f;
    float mu = p.stats[512 + tid] * inv;
    float var = p.stats[640 + tid] * inv - mu * mu;
    float s = p.bn2_g[tid] * rsqrtf(var + 1e-5f);
    bnc[tid] = s;
    bnc[128 + tid] = p.bn2_b[tid] - mu * s;
  }
  __syncthreads();
  for (int i = bid * 256 + tid; i < NNODES * 32; i += gsz) {
    int c = (i & 31) * 4;
    float4 a = ((const float4*)p.h2)[i];
    float4 o;
    o.x = a.x * bnc[c] + bnc[128 + c];
    o.y = a.y * bnc[c + 1] + bnc[129 + c];
    o.z = a.z * bnc[c + 2] + bnc[130 + c];
    o.w = a.w * bnc[c + 3] + bnc[131 + c];
    ((float4*)p.out)[i] = o;
  }
}

// ---------------------------------------------------------------------------
extern "C" void kernel_launch(void* const* d_in, const int* in_sizes, int n_in,
                              void* d_out, int out_size, void* d_ws, size_t ws_size,
                              hipStream_t stream)
{
  (void)in_sizes; (void)n_in; (void)out_size; (void)ws_size;
  char* ws = (char*)d_ws;
  const size_t KB = 1024, MB = 1048576;
  PK p;
  p.x      = (const float*)d_in[0];
  p.ei     = (const int*)d_in[1];
  p.ea     = (const float*)d_in[2];
  p.gw1    = (const float*)d_in[3];
  p.gb1    = (const float*)d_in[4];
  p.gw2    = (const float*)d_in[5];
  p.gb2    = (const float*)d_in[6];
  p.bn1l_g = (const float*)d_in[7];
  p.bn1l_b = (const float*)d_in[8];
  p.ipw    = (const float*)d_in[9];
  p.ipb    = (const float*)d_in[10];
  p.opw    = (const float*)d_in[11];
  p.opb    = (const float*)d_in[12];
  p.bn1a_g = (const float*)d_in[13];
  p.bn1a_b = (const float*)d_in[14];
  p.fw1    = (const float*)d_in[15];
  p.fb1    = (const float*)d_in[16];
  p.fw2    = (const float*)d_in[17];
  p.fb2    = (const float*)d_in[18];
  p.bn2_g  = (const float*)d_in[19];
  p.bn2_b  = (const float*)d_in[20];
  // workspace map (non-overlapping):
  // [0,320K) W | [320K,+3K) stats | [384K,448K) cnt | [448K,512K+4) off
  // [540K,542K) psum | [576K,640K) cur | [640K,2.625M) se
  // [3M,11M) z | [11M,19M) hl | [19M,23M) qb | [23M,27M) kb | [27M,31M) vb
  // [31M,39M) ob | [39M,47M) ha | [47M,55M) h2
  p.W     = (bf16*)(ws + 0);
  p.stats = (float*)(ws + 320 * KB);
  p.cnt   = (int*)(ws + 384 * KB);
  p.off   = (int*)(ws + 448 * KB);
  p.psum  = (int*)(ws + 540 * KB);
  p.cur   = (int*)(ws + 576 * KB);
  p.se    = (int2*)(ws + 640 * KB);
  p.z     = (float*)(ws + 3 * MB);
  p.hl    = (float*)(ws + 11 * MB);
  p.qb    = (bf16*)(ws + 19 * MB);
  p.kb    = (bf16*)(ws + 23 * MB);
  p.vb    = (bf16*)(ws + 27 * MB);
  p.ob    = (float*)(ws + 31 * MB);
  p.ha    = (float*)(ws + 39 * MB);
  p.h2    = (float*)(ws + 47 * MB);
  p.out   = (float*)d_out;

  int maxb = 1;
  (void)hipOccupancyMaxActiveBlocksPerMultiprocessor(&maxb, mega_k, 256, 0);
  int grid = (maxb >= 2) ? 512 : 256;
  void* args[] = { (void*)&p };
  (void)hipLaunchCooperativeKernel((void*)mega_k, dim3(grid), dim3(256),
                                   args, 0, stream);
}